// Round 1
// baseline (224.526 us; speedup 1.0000x reference)
//
#include <hip/hip_runtime.h>

// ---------------------------------------------------------------------------
// Decomposition (see round log):
//   qln = LN(qx)*g_q+b_q ; qhat = l2norm(qx) ; qxb = bf16(qx)
//   p   = qln @ wq^T ; pw = p @ wk  (via pre-transposed wk)
//   m2  = scale * pw * g_k ; t2 = scale * (pw . g_k)       [t1 dropped: softmax-invariant]
//   logits[q,n] = krstd_n * ( m2[q]·kx[n] - kmean_n * t2[q] ) (+mask)
//   numer = sum_n a_n * (qhat·kx_n) ;  denom^2 = a^T G[k] a,  G[k]=kx[k] kx[k]^T (symmetric)
//   x2 = exp(ls) * numer / max(denom,1e-12)
//   x1 = relu(qx@w1^T+b1) @ w2^T + b2
// All GEMMs bf16 MFMA 16x16x32, NT layout, f32 accum.
// ---------------------------------------------------------------------------

typedef unsigned short u16;
typedef short bf16x8s __attribute__((ext_vector_type(8)));
typedef float f32x4 __attribute__((ext_vector_type(4)));

#define SCALE_C 0.044194173824159216f  // 512^-0.5

__device__ __forceinline__ u16 f2bf(float f){
  union { float f; unsigned u; } c; c.f = f;
  unsigned u = c.u;
  return (u16)((u + 0x7fffu + ((u >> 16) & 1u)) >> 16);
}

// ---------------- workspace layout (bytes) ----------------
#define OFF_KXB  ((size_t)0)                         // 32768*512*2 = 33554432
#define OFF_G    (OFF_KXB + 33554432)                // 256*128*128*2 = 8388608
#define OFF_W2B  (OFF_G + 8388608)                   // 1000*2048*2 = 4096000
#define OFF_H    (OFF_W2B + 4096000)                 // 512*2048*2 = 2097152
#define OFF_W1B  (OFF_H + 2097152)                   // 2048*512*2 = 2097152
#define OFF_QLN  (OFF_W1B + 2097152)                 // 512*512*2 = 524288
#define OFF_QHAT (OFF_QLN + 524288)
#define OFF_QXB  (OFF_QHAT + 524288)
#define OFF_P    (OFF_QXB + 524288)
#define OFF_M2   (OFF_P + 524288)
#define OFF_WQB  (OFF_M2 + 524288)
#define OFF_WKT  (OFF_WQB + 524288)
#define OFF_PW   (OFF_WKT + 524288)                  // 512*512*4 = 1048576
#define OFF_KM   (OFF_PW + 1048576)                  // 32768*4
#define OFF_KR   (OFF_KM + 131072)
#define OFF_T2   (OFF_KR + 131072)                   // 512*4 (pad 4096)
#define OFF_FLAG (OFF_T2 + 4096)

// ---------------- mask dtype detection ----------------
// int32 mask: all words are 0/1.  byte mask: packed words are mostly >1.
__global__ void k_detect_mask(const int* __restrict__ mw, int* __restrict__ flag){
  __shared__ int smax;
  if (threadIdx.x == 0) smax = 0;
  __syncthreads();
  int mx = 0;
  for (int i = threadIdx.x; i < 8192; i += 256){
    int v = mw[i];
    mx = v > mx ? v : mx;
  }
  atomicMax(&smax, mx);
  __syncthreads();
  if (threadIdx.x == 0) *flag = (smax <= 1) ? 1 : 0;   // 1 => int32 mask
}

// ---------------- q-side prep: LN, l2norm, bf16 ----------------
__global__ void k_prep_q(const float* __restrict__ qx, const float* __restrict__ g_q,
                         const float* __restrict__ b_q, u16* __restrict__ qln,
                         u16* __restrict__ qhat, u16* __restrict__ qxb){
  __shared__ float red[2][2];
  const int row = blockIdx.x, t = threadIdx.x;  // 128 threads
  const float* x = qx + (size_t)row * 512;
  float4 v = *(const float4*)(x + t*4);
  float s  = v.x + v.y + v.z + v.w;
  float sq = v.x*v.x + v.y*v.y + v.z*v.z + v.w*v.w;
  #pragma unroll
  for (int o = 1; o < 64; o <<= 1){ s += __shfl_xor(s, o); sq += __shfl_xor(sq, o); }
  if ((t & 63) == 0){ red[t>>6][0] = s; red[t>>6][1] = sq; }
  __syncthreads();
  s = red[0][0] + red[1][0]; sq = red[0][1] + red[1][1];
  float mean = s * (1.0f/512.0f);
  float var  = sq * (1.0f/512.0f) - mean*mean;
  float rstd = rsqrtf(var + 1e-5f);
  float il2  = 1.0f / fmaxf(sqrtf(sq), 1e-12f);
  float vv[4] = {v.x, v.y, v.z, v.w};
  u16 oln[4], oh[4], ox[4];
  #pragma unroll
  for (int i = 0; i < 4; i++){
    int c = t*4 + i;
    oln[i] = f2bf((vv[i]-mean)*rstd*g_q[c] + b_q[c]);
    oh[i]  = f2bf(vv[i]*il2);
    ox[i]  = f2bf(vv[i]);
  }
  uint2 a, b, c2;
  a.x = oln[0] | ((unsigned)oln[1]<<16); a.y = oln[2] | ((unsigned)oln[3]<<16);
  b.x = oh[0]  | ((unsigned)oh[1]<<16);  b.y = oh[2]  | ((unsigned)oh[3]<<16);
  c2.x = ox[0] | ((unsigned)ox[1]<<16);  c2.y = ox[2] | ((unsigned)ox[3]<<16);
  *(uint2*)(qln  + (size_t)row*512 + t*4) = a;
  *(uint2*)(qhat + (size_t)row*512 + t*4) = b;
  *(uint2*)(qxb  + (size_t)row*512 + t*4) = c2;
}

// ---------------- k-side prep: row stats + bf16 ----------------
__global__ void k_prep_k(const float* __restrict__ kx, u16* __restrict__ kxb,
                         float* __restrict__ kmean, float* __restrict__ krstd){
  const int row  = blockIdx.x*4 + (threadIdx.x >> 6);
  const int lane = threadIdx.x & 63;
  const float* x = kx + (size_t)row * 512;
  float4 a = *(const float4*)(x + lane*8);
  float4 b = *(const float4*)(x + lane*8 + 4);
  float s  = a.x+a.y+a.z+a.w + b.x+b.y+b.z+b.w;
  float sq = a.x*a.x+a.y*a.y+a.z*a.z+a.w*a.w + b.x*b.x+b.y*b.y+b.z*b.z+b.w*b.w;
  #pragma unroll
  for (int o = 1; o < 64; o <<= 1){ s += __shfl_xor(s, o); sq += __shfl_xor(sq, o); }
  float mean = s * (1.0f/512.0f);
  float var  = sq * (1.0f/512.0f) - mean*mean;
  float rstd = rsqrtf(var + 1e-5f);
  u16 o8[8] = {f2bf(a.x),f2bf(a.y),f2bf(a.z),f2bf(a.w),f2bf(b.x),f2bf(b.y),f2bf(b.z),f2bf(b.w)};
  uint4 p;
  p.x = o8[0]|((unsigned)o8[1]<<16); p.y = o8[2]|((unsigned)o8[3]<<16);
  p.z = o8[4]|((unsigned)o8[5]<<16); p.w = o8[6]|((unsigned)o8[7]<<16);
  *(uint4*)(kxb + (size_t)row*512 + lane*8) = p;
  if (lane == 0){ kmean[row] = mean; krstd[row] = rstd; }
}

// ---------------- weight converts ----------------
__global__ void k_f32_to_bf16(const float* __restrict__ in, u16* __restrict__ out, int n4){
  int i = blockIdx.x*blockDim.x + threadIdx.x;
  if (i < n4){
    float4 v = *(const float4*)(in + (size_t)i*4);
    u16 o[4] = {f2bf(v.x),f2bf(v.y),f2bf(v.z),f2bf(v.w)};
    uint2 p; p.x = o[0]|((unsigned)o[1]<<16); p.y = o[2]|((unsigned)o[3]<<16);
    *(uint2*)(out + (size_t)i*4) = p;
  }
}

__global__ void k_transpose_bf16(const float* __restrict__ in, u16* __restrict__ out){
  __shared__ float tile[32][33];
  int bx = blockIdx.x*32, by = blockIdx.y*32;
  int tx = threadIdx.x, ty = threadIdx.y;   // (32,8)
  #pragma unroll
  for (int r = 0; r < 32; r += 8) tile[ty+r][tx] = in[(size_t)(by+ty+r)*512 + bx + tx];
  __syncthreads();
  #pragma unroll
  for (int r = 0; r < 32; r += 8) out[(size_t)(bx+ty+r)*512 + by + tx] = f2bf(tile[tx][ty+r]);
}

// ---------------- generic NT GEMM: C[i,j] = sum_c A[i,c]*B[j,c] ----------------
// 64x64 tile, 4 waves (2x2), K in 64-chunks, XOR-swizzled LDS.
template<int OUT_BF16, int RELU, int HAS_BIAS>
__global__ __launch_bounds__(256) void k_gemm_nt(
    const u16* __restrict__ A, const u16* __restrict__ B,
    void* __restrict__ Cv, const float* __restrict__ bias,
    int M, int N, int K, size_t sAz, size_t sBz, size_t sCz)
{
  __shared__ __align__(16) u16 lA[64][64];
  __shared__ __align__(16) u16 lB[64][64];
  const int tid = threadIdx.x;
  const int z = blockIdx.z;
  const u16* Ap = A + (size_t)z * sAz;
  const u16* Bp = B + (size_t)z * sBz;
  const int m0 = blockIdx.y * 64, n0 = blockIdx.x * 64;
  const int lane = tid & 63, w = tid >> 6;
  const int wr = (w >> 1) * 32, wc = (w & 1) * 32;
  const int l15 = lane & 15, lg = lane >> 4;
  f32x4 acc[2][2] = {};
  for (int kc = 0; kc < K; kc += 64){
    #pragma unroll
    for (int s = 0; s < 2; s++){
      int u = tid + s*256;
      int row = u >> 3, cg = u & 7;
      int sw = (cg ^ (row & 7)) * 8;
      uint4 va = make_uint4(0,0,0,0);
      if (m0 + row < M) va = *(const uint4*)(Ap + (size_t)(m0+row)*K + kc + cg*8);
      *(uint4*)&lA[row][sw] = va;
      uint4 vb = make_uint4(0,0,0,0);
      if (n0 + row < N) vb = *(const uint4*)(Bp + (size_t)(n0+row)*K + kc + cg*8);
      *(uint4*)&lB[row][sw] = vb;
    }
    __syncthreads();
    #pragma unroll
    for (int kk = 0; kk < 2; kk++){
      int cgr = kk*4 + lg;
      int ra0 = wr + l15, ra1 = wr + 16 + l15;
      int rb0 = wc + l15, rb1 = wc + 16 + l15;
      bf16x8s a0 = *(const bf16x8s*)&lA[ra0][(cgr ^ (ra0&7))*8];
      bf16x8s a1 = *(const bf16x8s*)&lA[ra1][(cgr ^ (ra1&7))*8];
      bf16x8s b0 = *(const bf16x8s*)&lB[rb0][(cgr ^ (rb0&7))*8];
      bf16x8s b1 = *(const bf16x8s*)&lB[rb1][(cgr ^ (rb1&7))*8];
      acc[0][0] = __builtin_amdgcn_mfma_f32_16x16x32_bf16(a0,b0,acc[0][0],0,0,0);
      acc[0][1] = __builtin_amdgcn_mfma_f32_16x16x32_bf16(a0,b1,acc[0][1],0,0,0);
      acc[1][0] = __builtin_amdgcn_mfma_f32_16x16x32_bf16(a1,b0,acc[1][0],0,0,0);
      acc[1][1] = __builtin_amdgcn_mfma_f32_16x16x32_bf16(a1,b1,acc[1][1],0,0,0);
    }
    __syncthreads();
  }
  #pragma unroll
  for (int i = 0; i < 2; i++){
    #pragma unroll
    for (int j = 0; j < 2; j++){
      int col = n0 + wc + j*16 + l15;
      if (col < N){
        float bv = HAS_BIAS ? bias[col] : 0.0f;
        #pragma unroll
        for (int r = 0; r < 4; r++){
          int row = m0 + wr + i*16 + lg*4 + r;
          if (row < M){
            float v = acc[i][j][r] + bv;
            if (RELU) v = fmaxf(v, 0.0f);
            if (OUT_BF16) ((u16*)Cv)[(size_t)z*sCz + (size_t)row*N + col] = f2bf(v);
            else          ((float*)Cv)[(size_t)z*sCz + (size_t)row*N + col] = v;
          }
        }
      }
    }
  }
}

// ---------------- pw epilogue: m2 = scale*pw*g_k (bf16), t2 = scale*(pw.g_k) ----------------
__global__ void k_pw_epi(const float* __restrict__ pw, const float* __restrict__ g_k,
                         u16* __restrict__ m2, float* __restrict__ t2s){
  __shared__ float red[2];
  const int row = blockIdx.x, t = threadIdx.x;  // 128 threads
  float4 v = *(const float4*)(pw + (size_t)row*512 + t*4);
  float4 g = *(const float4*)(g_k + t*4);
  float e0 = SCALE_C*v.x*g.x, e1 = SCALE_C*v.y*g.y, e2 = SCALE_C*v.z*g.z, e3 = SCALE_C*v.w*g.w;
  u16 o[4] = {f2bf(e0),f2bf(e1),f2bf(e2),f2bf(e3)};
  uint2 p; p.x = o[0]|((unsigned)o[1]<<16); p.y = o[2]|((unsigned)o[3]<<16);
  *(uint2*)(m2 + (size_t)row*512 + t*4) = p;
  float s = e0+e1+e2+e3;
  #pragma unroll
  for (int o2 = 1; o2 < 64; o2 <<= 1) s += __shfl_xor(s, o2);
  if ((t & 63) == 0){ if (t == 0) red[0] = s; else red[1] = s; }
  __syncthreads();
  if (t == 0) t2s[row] = red[0] + red[1];
}

// ---------------- fused attention: logits + softmax + numer + denom + x2 ----------------
// block: one (k in 0..255, q-tile of 64). 256 thr = 4 waves (2 row x 2 col).
__global__ __launch_bounds__(256) void k_attn(
    const u16* __restrict__ kxb, const u16* __restrict__ Gm,
    const u16* __restrict__ m2, const u16* __restrict__ qhat,
    const float* __restrict__ kmean, const float* __restrict__ krstd,
    const float* __restrict__ t2s, const void* __restrict__ maskp,
    const int* __restrict__ flagp, const float* __restrict__ lsp,
    float* __restrict__ x2)
{
  __shared__ __align__(16) u16 lKX[128][64];
  __shared__ __align__(16) u16 lM2[64][64];
  __shared__ __align__(16) u16 lQH[64][64];
  __shared__ __align__(16) u16 lP[64][128];
  __shared__ float lkm[128], lkr[128], lmb[128], lt2[64];
  __shared__ float lZ[64][2], lNum[64][2], lDen[64][2];

  const int kb = blockIdx.x, qt = blockIdx.y;
  const int q0 = qt * 64;
  const int tid = threadIdx.x;
  const int lane = tid & 63, w = tid >> 6;
  const int wr = (w >> 1) * 32;
  const int wcol = (w & 1) * 64;
  const int l15 = lane & 15, lg = lane >> 4;

  if (tid < 128){
    int n = tid;
    lkm[n] = kmean[kb*128 + n];
    lkr[n] = krstd[kb*128 + n];
    int mv = (*flagp) ? ((const int*)maskp)[kb*128+n]
                      : (int)((const unsigned char*)maskp)[kb*128+n];
    lmb[n] = mv ? -1e30f : 0.0f;
  } else if (tid < 192){
    lt2[tid - 128] = t2s[q0 + (tid - 128)];
  }

  const u16* KX = kxb + (size_t)kb * (128*512);
  f32x4 aS[2][4] = {};
  f32x4 aD[2][4] = {};

  for (int kc = 0; kc < 512; kc += 64){
    #pragma unroll
    for (int s = 0; s < 4; s++){
      int u = tid + s*256;
      int row = u >> 3, cg = u & 7;
      *(uint4*)&lKX[row][(cg ^ (row & 7)) * 8] =
        *(const uint4*)(KX + (size_t)row*512 + kc + cg*8);
    }
    #pragma unroll
    for (int s = 0; s < 2; s++){
      int u = tid + s*256;
      int row = u >> 3, cg = u & 7;
      size_t go = (size_t)(q0 + row)*512 + kc + cg*8;
      int sw = (cg ^ (row & 7)) * 8;
      *(uint4*)&lM2[row][sw] = *(const uint4*)(m2 + go);
      *(uint4*)&lQH[row][sw] = *(const uint4*)(qhat + go);
    }
    __syncthreads();
    #pragma unroll
    for (int kk = 0; kk < 2; kk++){
      int cgr = kk*4 + lg;
      int rA0 = wr + l15, rA1 = wr + 16 + l15;
      bf16x8s am0 = *(const bf16x8s*)&lM2[rA0][(cgr ^ (rA0&7))*8];
      bf16x8s am1 = *(const bf16x8s*)&lM2[rA1][(cgr ^ (rA1&7))*8];
      bf16x8s aq0 = *(const bf16x8s*)&lQH[rA0][(cgr ^ (rA0&7))*8];
      bf16x8s aq1 = *(const bf16x8s*)&lQH[rA1][(cgr ^ (rA1&7))*8];
      #pragma unroll
      for (int j = 0; j < 4; j++){
        int rB = wcol + j*16 + l15;
        bf16x8s bk = *(const bf16x8s*)&lKX[rB][(cgr ^ (rB&7))*8];
        aS[0][j] = __builtin_amdgcn_mfma_f32_16x16x32_bf16(am0, bk, aS[0][j], 0,0,0);
        aS[1][j] = __builtin_amdgcn_mfma_f32_16x16x32_bf16(am1, bk, aS[1][j], 0,0,0);
        aD[0][j] = __builtin_amdgcn_mfma_f32_16x16x32_bf16(aq0, bk, aD[0][j], 0,0,0);
        aD[1][j] = __builtin_amdgcn_mfma_f32_16x16x32_bf16(aq1, bk, aD[1][j], 0,0,0);
      }
    }
    __syncthreads();
  }

  // softmax (no max-sub: |logits| < ~2 by construction) + numerator partials
  #pragma unroll
  for (int i = 0; i < 2; i++){
    #pragma unroll
    for (int r = 0; r < 4; r++){
      int rowl = wr + i*16 + lg*4 + r;
      float t2v = lt2[rowl];
      float se = 0.f, sn = 0.f;
      #pragma unroll
      for (int j = 0; j < 4; j++){
        int n = wcol + j*16 + l15;
        float L = lkr[n]*(aS[i][j][r] - lkm[n]*t2v) + lmb[n];
        float e = __expf(L);
        aS[i][j][r] = e;
        se += e;
        sn += e * aD[i][j][r];
      }
      #pragma unroll
      for (int o = 1; o < 16; o <<= 1){ se += __shfl_xor(se, o); sn += __shfl_xor(sn, o); }
      if (l15 == 0){ lZ[rowl][w & 1] = se; lNum[rowl][w & 1] = sn; }
    }
  }
  __syncthreads();

  // normalize -> P (regs f32 + LDS bf16, swizzled)
  #pragma unroll
  for (int i = 0; i < 2; i++){
    #pragma unroll
    for (int r = 0; r < 4; r++){
      int rowl = wr + i*16 + lg*4 + r;
      float Zi = 1.0f / (lZ[rowl][0] + lZ[rowl][1]);
      #pragma unroll
      for (int j = 0; j < 4; j++){
        int n = wcol + j*16 + l15;
        float p = aS[i][j][r] * Zi;
        aS[i][j][r] = p;
        lP[rowl][((n>>3) ^ (rowl&7))*8 + (n&7)] = f2bf(p);
      }
    }
  }
  __syncthreads();

  // T = P @ G  (G symmetric -> row-major B-frags straight from global; L2-hot)
  f32x4 aT[2][4] = {};
  const u16* Gk = Gm + (size_t)kb * (128*128);
  #pragma unroll
  for (int kk = 0; kk < 4; kk++){
    int cgr = kk*4 + lg;
    int rA0 = wr + l15, rA1 = wr + 16 + l15;
    bf16x8s p0 = *(const bf16x8s*)&lP[rA0][(cgr ^ (rA0&7))*8];
    bf16x8s p1 = *(const bf16x8s*)&lP[rA1][(cgr ^ (rA1&7))*8];
    #pragma unroll
    for (int j = 0; j < 4; j++){
      int mcol = wcol + j*16 + l15;
      bf16x8s bg = *(const bf16x8s*)(Gk + (size_t)mcol*128 + kk*32 + lg*8);
      aT[0][j] = __builtin_amdgcn_mfma_f32_16x16x32_bf16(p0, bg, aT[0][j], 0,0,0);
      aT[1][j] = __builtin_amdgcn_mfma_f32_16x16x32_bf16(p1, bg, aT[1][j], 0,0,0);
    }
  }
  // denom^2 partials
  #pragma unroll
  for (int i = 0; i < 2; i++){
    #pragma unroll
    for (int r = 0; r < 4; r++){
      int rowl = wr + i*16 + lg*4 + r;
      float sd = 0.f;
      #pragma unroll
      for (int j = 0; j < 4; j++) sd += aT[i][j][r] * aS[i][j][r];
      #pragma unroll
      for (int o = 1; o < 16; o <<= 1) sd += __shfl_xor(sd, o);
      if (l15 == 0) lDen[rowl][w & 1] = sd;
    }
  }
  __syncthreads();

  if (tid < 64){
    int rowl = tid;
    float Z    = lZ[rowl][0] + lZ[rowl][1];
    float num  = (lNum[rowl][0] + lNum[rowl][1]) / Z;
    float den2 = lDen[rowl][0] + lDen[rowl][1];
    float den  = fmaxf(sqrtf(fmaxf(den2, 0.0f)), 1e-12f);
    x2[(size_t)(q0 + rowl)*256 + kb] = expf(lsp[0]) * num / den;
  }
}

// ---------------------------------------------------------------------------
extern "C" void kernel_launch(void* const* d_in, const int* in_sizes, int n_in,
                              void* d_out, int out_size, void* d_ws, size_t ws_size,
                              hipStream_t stream)
{
  (void)in_sizes; (void)n_in; (void)out_size; (void)ws_size;
  const float* qx  = (const float*)d_in[0];
  const float* kx  = (const float*)d_in[1];
  const void*  mask= d_in[2];
  const float* lsp = (const float*)d_in[3];
  const float* g_q = (const float*)d_in[4];
  const float* b_q = (const float*)d_in[5];
  const float* g_k = (const float*)d_in[6];
  // d_in[7] (b_k) unused: contributes a per-q constant to logits -> softmax-invariant
  const float* wq  = (const float*)d_in[8];
  const float* wk  = (const float*)d_in[9];
  const float* w1  = (const float*)d_in[10];
  const float* b1  = (const float*)d_in[11];
  const float* w2  = (const float*)d_in[12];
  const float* b2  = (const float*)d_in[13];

  char* ws = (char*)d_ws;
  u16* kxb  = (u16*)(ws + OFF_KXB);
  u16* Gm   = (u16*)(ws + OFF_G);
  u16* w2b  = (u16*)(ws + OFF_W2B);
  u16* hbuf = (u16*)(ws + OFF_H);
  u16* w1b  = (u16*)(ws + OFF_W1B);
  u16* qln  = (u16*)(ws + OFF_QLN);
  u16* qhat = (u16*)(ws + OFF_QHAT);
  u16* qxb  = (u16*)(ws + OFF_QXB);
  u16* pbuf = (u16*)(ws + OFF_P);
  u16* m2   = (u16*)(ws + OFF_M2);
  u16* wqb  = (u16*)(ws + OFF_WQB);
  u16* wkt  = (u16*)(ws + OFF_WKT);
  float* pw  = (float*)(ws + OFF_PW);
  float* km  = (float*)(ws + OFF_KM);
  float* kr  = (float*)(ws + OFF_KR);
  float* t2s = (float*)(ws + OFF_T2);
  int*   flag= (int*)(ws + OFF_FLAG);
  float* x1o = (float*)d_out;
  float* x2o = (float*)d_out + 512*1000;

  k_detect_mask<<<dim3(1), dim3(256), 0, stream>>>((const int*)mask, flag);
  k_prep_q<<<dim3(512), dim3(128), 0, stream>>>(qx, g_q, b_q, qln, qhat, qxb);
  k_prep_k<<<dim3(8192), dim3(256), 0, stream>>>(kx, kxb, km, kr);
  k_f32_to_bf16<<<dim3(256), dim3(256), 0, stream>>>(wq, wqb, 65536);
  k_transpose_bf16<<<dim3(16,16), dim3(32,8), 0, stream>>>(wk, wkt);
  k_f32_to_bf16<<<dim3(1024), dim3(256), 0, stream>>>(w1, w1b, 262144);
  k_f32_to_bf16<<<dim3(2000), dim3(256), 0, stream>>>(w2, w2b, 512000);

  // p = qln @ wq^T
  k_gemm_nt<1,0,0><<<dim3(8,8,1), dim3(256), 0, stream>>>(
      qln, wqb, (void*)pbuf, (const float*)nullptr, 512,512,512, 0,0,0);
  // pw = p @ wk  (B = wk^T pre-transposed)
  k_gemm_nt<0,0,0><<<dim3(8,8,1), dim3(256), 0, stream>>>(
      pbuf, wkt, (void*)pw, (const float*)nullptr, 512,512,512, 0,0,0);
  k_pw_epi<<<dim3(512), dim3(128), 0, stream>>>(pw, g_k, m2, t2s);
  // G[k] = kxb[k] @ kxb[k]^T (batched)
  k_gemm_nt<1,0,0><<<dim3(2,2,256), dim3(256), 0, stream>>>(
      kxb, kxb, (void*)Gm, (const float*)nullptr, 128,128,512,
      (size_t)65536, (size_t)65536, (size_t)16384);
  // h = relu(qx @ w1^T + b1)
  k_gemm_nt<1,1,1><<<dim3(32,8,1), dim3(256), 0, stream>>>(
      qxb, w1b, (void*)hbuf, b1, 512,2048,512, 0,0,0);
  // x1 = h @ w2^T + b2
  k_gemm_nt<0,0,1><<<dim3(16,8,1), dim3(256), 0, stream>>>(
      hbuf, w2b, (void*)x1o, b2, 512,1000,2048, 0,0,0);
  // fused attention -> x2
  k_attn<<<dim3(256,8), dim3(256), 0, stream>>>(
      kxb, Gm, m2, qhat, km, kr, t2s, mask, flag, lsp, x2o);
}

// Round 2
// 152.642 us; speedup vs baseline: 1.4709x; 1.4709x over previous
//
#include <hip/hip_runtime.h>

typedef unsigned short u16;
typedef unsigned int u32;
typedef short bf16x8s __attribute__((ext_vector_type(8)));
typedef float f32x4 __attribute__((ext_vector_type(4)));

#define SCALE_C 0.044194173824159216f  // 512^-0.5
#define MFMA16 __builtin_amdgcn_mfma_f32_16x16x32_bf16

__device__ __forceinline__ u16 f2bf(float f){
  union { float f; u32 u; } c; c.f = f;
  u32 u = c.u;
  return (u16)((u + 0x7fffu + ((u >> 16) & 1u)) >> 16);
}

// global -> LDS direct DMA, 16B per lane. LDS dest must be wave-uniform base
// (HW writes base + lane*16); global src is per-lane (carries the swizzle).
__device__ __forceinline__ void gload16(const void* g, void* l){
  __builtin_amdgcn_global_load_lds((const __attribute__((address_space(1))) void*)g,
                                   (__attribute__((address_space(3))) void*)l, 16, 0, 0);
}

// ---------------- workspace layout (bytes) ----------------
#define OFF_KXB  ((size_t)0)                  // 32768*512*2
#define OFF_G    (OFF_KXB + 33554432)         // 256*128*128*2
#define OFF_W2B  (OFF_G + 8388608)            // 1000*2048*2
#define OFF_H    (OFF_W2B + 4096000)          // 512*2048*2
#define OFF_W1B  (OFF_H + 2097152)            // 2048*512*2
#define OFF_QLN  (OFF_W1B + 2097152)          // 512*512*2 each below
#define OFF_QHAT (OFF_QLN + 524288)
#define OFF_QXB  (OFF_QHAT + 524288)
#define OFF_P    (OFF_QXB + 524288)
#define OFF_M2   (OFF_P + 524288)
#define OFF_WQB  (OFF_M2 + 524288)
#define OFF_WKT  (OFF_WQB + 524288)
#define OFF_KM   (OFF_WKT + 524288)           // 32768*4
#define OFF_KR   (OFF_KM + 131072)
#define OFF_T2   (OFF_KR + 131072)            // 512*4
#define OFF_FLAG (OFF_T2 + 4096)

// ===================== PHASE A: all prep, one launch =====================
// [0,8192)      prep_k (4 rows/block)
// [8192,8704)   prep_q (1 row/block, 256 thr)
// [8704,8960)   cvt wq   [8960,9984) cvt w1   [9984,11984) cvt w2
// [11984,12240) transpose wk -> wkt
// 12240         mask-dtype detect + zero t2s
__global__ __launch_bounds__(256) void k_phaseA(
    const float* __restrict__ qx, const float* __restrict__ kx,
    const int* __restrict__ maskw,
    const float* __restrict__ g_q, const float* __restrict__ b_q,
    const float* __restrict__ wq, const float* __restrict__ wk,
    const float* __restrict__ w1, const float* __restrict__ w2,
    u16* __restrict__ kxb, float* __restrict__ km, float* __restrict__ kr,
    u16* __restrict__ qln, u16* __restrict__ qhat, u16* __restrict__ qxb,
    u16* __restrict__ wqb, u16* __restrict__ wkt, u16* __restrict__ w1b,
    u16* __restrict__ w2b, float* __restrict__ t2s, int* __restrict__ flag)
{
  const int bid = blockIdx.x, tid = threadIdx.x;
  if (bid < 8192){
    const int row = bid*4 + (tid>>6);
    const int lane = tid & 63;
    const float* x = kx + (size_t)row*512;
    float4 a = *(const float4*)(x + lane*8);
    float4 b = *(const float4*)(x + lane*8 + 4);
    float s  = a.x+a.y+a.z+a.w + b.x+b.y+b.z+b.w;
    float sq = a.x*a.x+a.y*a.y+a.z*a.z+a.w*a.w + b.x*b.x+b.y*b.y+b.z*b.z+b.w*b.w;
    #pragma unroll
    for (int o = 1; o < 64; o <<= 1){ s += __shfl_xor(s,o); sq += __shfl_xor(sq,o); }
    float mean = s*(1.0f/512.0f);
    float var  = sq*(1.0f/512.0f) - mean*mean;
    float rstd = rsqrtf(var + 1e-5f);
    uint4 p;
    p.x = f2bf(a.x)|((u32)f2bf(a.y)<<16); p.y = f2bf(a.z)|((u32)f2bf(a.w)<<16);
    p.z = f2bf(b.x)|((u32)f2bf(b.y)<<16); p.w = f2bf(b.z)|((u32)f2bf(b.w)<<16);
    *(uint4*)(kxb + (size_t)row*512 + lane*8) = p;
    if (lane == 0){ km[row] = mean; kr[row] = rstd; }
  } else if (bid < 8704){
    __shared__ float redq[4][2];
    const int row = bid - 8192;
    const int lane = tid & 63, wv = tid >> 6;
    float2 v = *(const float2*)(qx + (size_t)row*512 + tid*2);
    float s = v.x+v.y, sq = v.x*v.x+v.y*v.y;
    #pragma unroll
    for (int o = 1; o < 64; o <<= 1){ s += __shfl_xor(s,o); sq += __shfl_xor(sq,o); }
    if (lane == 0){ redq[wv][0]=s; redq[wv][1]=sq; }
    __syncthreads();
    s  = redq[0][0]+redq[1][0]+redq[2][0]+redq[3][0];
    sq = redq[0][1]+redq[1][1]+redq[2][1]+redq[3][1];
    float mean = s*(1.0f/512.0f);
    float var  = sq*(1.0f/512.0f) - mean*mean;
    float rstd = rsqrtf(var + 1e-5f);
    float il2  = 1.0f / fmaxf(sqrtf(sq), 1e-12f);
    float2 g  = *(const float2*)(g_q + tid*2);
    float2 bb = *(const float2*)(b_q + tid*2);
    u32 a  = f2bf((v.x-mean)*rstd*g.x+bb.x) | ((u32)f2bf((v.y-mean)*rstd*g.y+bb.y)<<16);
    u32 h  = f2bf(v.x*il2) | ((u32)f2bf(v.y*il2)<<16);
    u32 xx = f2bf(v.x)     | ((u32)f2bf(v.y)<<16);
    *(u32*)(qln  + (size_t)row*512 + tid*2) = a;
    *(u32*)(qhat + (size_t)row*512 + tid*2) = h;
    *(u32*)(qxb  + (size_t)row*512 + tid*2) = xx;
  } else if (bid < 11984){
    const float* in; u16* out; int i;
    if (bid < 8960)      { in = wq; out = wqb; i = (bid-8704)*256 + tid; }
    else if (bid < 9984) { in = w1; out = w1b; i = (bid-8960)*256 + tid; }
    else                 { in = w2; out = w2b; i = (bid-9984)*256 + tid; }
    float4 v = *(const float4*)(in + (size_t)i*4);
    uint2 p;
    p.x = f2bf(v.x)|((u32)f2bf(v.y)<<16); p.y = f2bf(v.z)|((u32)f2bf(v.w)<<16);
    *(uint2*)(out + (size_t)i*4) = p;
  } else if (bid < 12240){
    __shared__ float tile[32][33];
    const int t = bid - 11984;
    const int bx = (t & 15)*32, by = (t >> 4)*32;
    const int tx = tid & 31, ty = tid >> 5;  // 8 rows
    #pragma unroll
    for (int r = 0; r < 32; r += 8) tile[ty+r][tx] = wk[(size_t)(by+ty+r)*512 + bx+tx];
    __syncthreads();
    #pragma unroll
    for (int r = 0; r < 32; r += 8) wkt[(size_t)(bx+ty+r)*512 + by+tx] = f2bf(tile[tx][ty+r]);
  } else {
    __shared__ int smax;
    if (tid == 0) smax = 0;
    t2s[tid] = 0.0f; t2s[tid+256] = 0.0f;
    __syncthreads();
    int mx = 0;
    for (int i = tid; i < 8192; i += 256){ int v = maskw[i]; mx = v > mx ? v : mx; }
    #pragma unroll
    for (int o = 1; o < 64; o <<= 1){ int t2 = __shfl_xor(mx,o); mx = t2 > mx ? t2 : mx; }
    if ((tid & 63) == 0) atomicMax(&smax, mx);
    __syncthreads();
    if (tid == 0) *flag = (smax <= 1) ? 1 : 0;
  }
}

// ------------- round-1-proven 64x64 GEMM body (register-staged) -------------
__device__ __forceinline__ void gemm_body(const u16* __restrict__ Ap, const u16* __restrict__ Bp,
    int M, int N, int K, int m0, int n0, int tid,
    u16 (*lA)[64], u16 (*lB)[64], f32x4 (&acc)[2][2])
{
  const int lane = tid & 63, w = tid >> 6;
  const int wr = (w >> 1)*32, wc = (w & 1)*32;
  const int l15 = lane & 15, lg = lane >> 4;
  for (int kc = 0; kc < K; kc += 64){
    #pragma unroll
    for (int s = 0; s < 2; s++){
      int u = tid + s*256;
      int row = u >> 3, cg = u & 7;
      int sw = (cg ^ (row & 7)) * 8;
      uint4 va = make_uint4(0,0,0,0);
      if (m0 + row < M) va = *(const uint4*)(Ap + (size_t)(m0+row)*K + kc + cg*8);
      *(uint4*)&lA[row][sw] = va;
      uint4 vb = make_uint4(0,0,0,0);
      if (n0 + row < N) vb = *(const uint4*)(Bp + (size_t)(n0+row)*K + kc + cg*8);
      *(uint4*)&lB[row][sw] = vb;
    }
    __syncthreads();
    #pragma unroll
    for (int kk = 0; kk < 2; kk++){
      int cgr = kk*4 + lg;
      int ra0 = wr + l15, ra1 = wr + 16 + l15;
      int rb0 = wc + l15, rb1 = wc + 16 + l15;
      bf16x8s a0 = *(const bf16x8s*)&lA[ra0][(cgr ^ (ra0&7))*8];
      bf16x8s a1 = *(const bf16x8s*)&lA[ra1][(cgr ^ (ra1&7))*8];
      bf16x8s b0 = *(const bf16x8s*)&lB[rb0][(cgr ^ (rb0&7))*8];
      bf16x8s b1 = *(const bf16x8s*)&lB[rb1][(cgr ^ (rb1&7))*8];
      acc[0][0] = MFMA16(a0,b0,acc[0][0],0,0,0);
      acc[0][1] = MFMA16(a0,b1,acc[0][1],0,0,0);
      acc[1][0] = MFMA16(a1,b0,acc[1][0],0,0,0);
      acc[1][1] = MFMA16(a1,b1,acc[1][1],0,0,0);
    }
    __syncthreads();
  }
}

__device__ __forceinline__ void store_tile(void* C, int ldc, int m0, int n0, int M, int N,
    const float* bias, int relu, int bf16out, f32x4 (&acc)[2][2], int tid)
{
  const int lane = tid & 63, w = tid >> 6;
  const int wr = (w >> 1)*32, wc = (w & 1)*32;
  const int l15 = lane & 15, lg = lane >> 4;
  #pragma unroll
  for (int i = 0; i < 2; i++){
    #pragma unroll
    for (int j = 0; j < 2; j++){
      int col = n0 + wc + j*16 + l15;
      if (col < N){
        float bv = bias ? bias[col] : 0.0f;
        #pragma unroll
        for (int r = 0; r < 4; r++){
          int row = m0 + wr + i*16 + lg*4 + r;
          if (row < M){
            float v = acc[i][j][r] + bv;
            if (relu) v = fmaxf(v, 0.0f);
            if (bf16out) ((u16*)C)[(size_t)row*ldc + col] = f2bf(v);
            else         ((float*)C)[(size_t)row*ldc + col] = v;
          }
        }
      }
    }
  }
}

// ===================== PHASE B: p-GEMM + Gram + h-GEMM =====================
__global__ __launch_bounds__(256) void k_phaseB(
    const u16* __restrict__ qln, const u16* __restrict__ wqb, u16* __restrict__ pbuf,
    const u16* __restrict__ kxb, u16* __restrict__ Gm,
    const u16* __restrict__ qxb, const u16* __restrict__ w1b,
    const float* __restrict__ b1, u16* __restrict__ hbuf)
{
  __shared__ __align__(16) u16 lA[64][64], lB[64][64];
  f32x4 acc[2][2] = {};
  const int bid = blockIdx.x, tid = threadIdx.x;
  if (bid < 64){
    int m0 = (bid>>3)*64, n0 = (bid&7)*64;
    gemm_body(qln, wqb, 512,512,512, m0,n0, tid, lA, lB, acc);
    store_tile(pbuf, 512, m0,n0, 512,512, nullptr, 0, 1, acc, tid);
  } else if (bid < 1088){
    int b = bid-64, z = b>>2, m0 = ((b>>1)&1)*64, n0 = (b&1)*64;
    const u16* kz = kxb + (size_t)z*65536;
    gemm_body(kz, kz, 128,128,512, m0,n0, tid, lA, lB, acc);
    store_tile(Gm + (size_t)z*16384, 128, m0,n0, 128,128, nullptr, 0, 1, acc, tid);
  } else {
    int b = bid-1088, m0 = (b>>5)*64, n0 = (b&31)*64;
    gemm_body(qxb, w1b, 512,2048,512, m0,n0, tid, lA, lB, acc);
    store_tile(hbuf, 2048, m0,n0, 512,2048, b1, 1, 1, acc, tid);
  }
}

// ============ PHASE C: pw-GEMM (fused m2/t2 epilogue) + x1-GEMM ============
__global__ __launch_bounds__(256) void k_phaseC(
    const u16* __restrict__ pbuf, const u16* __restrict__ wkt,
    const float* __restrict__ g_k, u16* __restrict__ m2, float* __restrict__ t2s,
    const u16* __restrict__ hbuf, const u16* __restrict__ w2b,
    const float* __restrict__ b2, float* __restrict__ x1o)
{
  __shared__ __align__(16) u16 lA[64][64], lB[64][64];
  f32x4 acc[2][2] = {};
  const int bid = blockIdx.x, tid = threadIdx.x;
  const int lane = tid & 63, w = tid >> 6;
  const int wr = (w >> 1)*32, wc = (w & 1)*32;
  const int l15 = lane & 15, lg = lane >> 4;
  if (bid < 64){
    int m0 = (bid>>3)*64, n0 = (bid&7)*64;
    gemm_body(pbuf, wkt, 512,512,512, m0,n0, tid, lA, lB, acc);
    #pragma unroll
    for (int i = 0; i < 2; i++){
      #pragma unroll
      for (int r = 0; r < 4; r++){
        int row = m0 + wr + i*16 + lg*4 + r;
        float part = 0.f;
        #pragma unroll
        for (int j = 0; j < 2; j++){
          int col = n0 + wc + j*16 + l15;
          float e = SCALE_C * acc[i][j][r] * g_k[col];
          m2[(size_t)row*512 + col] = f2bf(e);
          part += e;
        }
        #pragma unroll
        for (int o = 1; o < 16; o <<= 1) part += __shfl_xor(part, o);
        if (l15 == 0) atomicAdd(&t2s[row], part);
      }
    }
  } else {
    int b = bid-64, m0 = (b>>4)*64, n0 = (b&15)*64;
    gemm_body(hbuf, w2b, 512,1000,2048, m0,n0, tid, lA, lB, acc);
    store_tile(x1o, 1000, m0,n0, 512,1000, b2, 0, 0, acc, tid);
  }
}

// ===================== PHASE D: fused attention -> x2 =====================
// block = (kb, q-tile of 128); 512 thr = 8 waves (4 qrow-groups x 2 ncol-halves)
__global__ __launch_bounds__(512, 4) void k_attn(
    const u16* __restrict__ kxb, const u16* __restrict__ Gm,
    const u16* __restrict__ m2, const u16* __restrict__ qhat,
    const float* __restrict__ km, const float* __restrict__ kr,
    const float* __restrict__ t2s, const void* __restrict__ maskp,
    const int* __restrict__ flagp, const float* __restrict__ lsp,
    float* __restrict__ x2)
{
  __shared__ __align__(16) u16 lBig[3*8192];   // 48KB: KX|M2|QH ; P aliases [0,16384)
  __shared__ float lkm[128], lkr[128], lmb[128], lt2[128];
  __shared__ float lZ[128][2], lNum[128][2], lDen[128][2];
  u16* lKX = lBig;           // [128][64] swizzled
  u16* lM2 = lBig + 8192;    // [128][64]
  u16* lQH = lBig + 16384;   // [128][64]
  u16* lP  = lBig;           // [128][128] (after main loop)

  const int kb = blockIdx.x, q0 = blockIdx.y * 128;
  const int tid = threadIdx.x, lane = tid & 63, w = tid >> 6;
  const int wr = (w >> 1)*32, wcol = (w & 1)*64;
  const int l15 = lane & 15, lg = lane >> 4;

  if (tid < 128) lt2[tid] = t2s[q0 + tid];
  else if (tid < 256){
    int n = tid - 128;
    lkm[n] = km[kb*128 + n];
    lkr[n] = kr[kb*128 + n];
    int mv = (*flagp) ? ((const int*)maskp)[kb*128+n]
                      : (int)((const unsigned char*)maskp)[kb*128+n];
    lmb[n] = mv ? -1e30f : 0.0f;
  }

  const u16* KX = kxb + (size_t)kb * 65536;
  f32x4 aS[2][4] = {}, aD[2][4] = {};

  for (int kc = 0; kc < 512; kc += 64){
    // stage: wave w loads rows [w*16, w*16+16) of each tile; linear LDS dest,
    // inverse-XOR-swizzled global source (read side applies the same XOR).
    #pragma unroll
    for (int i = 0; i < 2; i++){
      int row = w*16 + i*8 + (lane >> 3);
      int cgs = (lane & 7) ^ (row & 7);
      int ldsoff = (w*16 + i*8) * 64;
      gload16(KX   + (size_t)row*512      + kc + cgs*8, lKX + ldsoff);
      gload16(m2   + (size_t)(q0+row)*512 + kc + cgs*8, lM2 + ldsoff);
      gload16(qhat + (size_t)(q0+row)*512 + kc + cgs*8, lQH + ldsoff);
    }
    __syncthreads();
    #pragma unroll
    for (int kk = 0; kk < 2; kk++){
      int cgr = kk*4 + lg;
      int rA0 = wr + l15, rA1 = wr + 16 + l15;
      bf16x8s am0 = *(const bf16x8s*)&lM2[rA0*64 + (cgr^(rA0&7))*8];
      bf16x8s am1 = *(const bf16x8s*)&lM2[rA1*64 + (cgr^(rA1&7))*8];
      bf16x8s aq0 = *(const bf16x8s*)&lQH[rA0*64 + (cgr^(rA0&7))*8];
      bf16x8s aq1 = *(const bf16x8s*)&lQH[rA1*64 + (cgr^(rA1&7))*8];
      #pragma unroll
      for (int j = 0; j < 4; j++){
        int rB = wcol + j*16 + l15;
        bf16x8s bk = *(const bf16x8s*)&lKX[rB*64 + (cgr^(rB&7))*8];
        aS[0][j] = MFMA16(am0, bk, aS[0][j], 0,0,0);
        aS[1][j] = MFMA16(am1, bk, aS[1][j], 0,0,0);
        aD[0][j] = MFMA16(aq0, bk, aD[0][j], 0,0,0);
        aD[1][j] = MFMA16(aq1, bk, aD[1][j], 0,0,0);
      }
    }
    __syncthreads();
  }

  // softmax partials (no max-sub: logits bounded by construction)
  #pragma unroll
  for (int i = 0; i < 2; i++){
    #pragma unroll
    for (int r = 0; r < 4; r++){
      int rowl = wr + i*16 + lg*4 + r;
      float t2v = lt2[rowl];
      float se = 0.f, sn = 0.f;
      #pragma unroll
      for (int j = 0; j < 4; j++){
        int n = wcol + j*16 + l15;
        float L = lkr[n]*(aS[i][j][r] - lkm[n]*t2v) + lmb[n];
        float e = __expf(L);
        aS[i][j][r] = e;
        se += e;
        sn += e * aD[i][j][r];
      }
      #pragma unroll
      for (int o = 1; o < 16; o <<= 1){ se += __shfl_xor(se,o); sn += __shfl_xor(sn,o); }
      if (l15 == 0){ lZ[rowl][w&1] = se; lNum[rowl][w&1] = sn; }
    }
  }
  __syncthreads();

  // normalize -> P (bf16 in LDS, swizzled; aliases dead KX/M2 region)
  #pragma unroll
  for (int i = 0; i < 2; i++){
    #pragma unroll
    for (int r = 0; r < 4; r++){
      int rowl = wr + i*16 + lg*4 + r;
      float Zi = 1.0f / (lZ[rowl][0] + lZ[rowl][1]);
      #pragma unroll
      for (int j = 0; j < 4; j++){
        int n = wcol + j*16 + l15;
        float p = aS[i][j][r] * Zi;
        aS[i][j][r] = p;
        lP[rowl*128 + ((n>>3)^(rowl&7))*8 + (n&7)] = f2bf(p);
      }
    }
  }
  __syncthreads();

  // T = P @ G (G symmetric: row-major B-frags straight from global, L2-hot)
  f32x4 aT[2][4] = {};
  const u16* Gk = Gm + (size_t)kb * 16384;
  #pragma unroll
  for (int kk = 0; kk < 4; kk++){
    int cgr = kk*4 + lg;
    int rA0 = wr + l15, rA1 = wr + 16 + l15;
    bf16x8s p0 = *(const bf16x8s*)&lP[rA0*128 + (cgr^(rA0&7))*8];
    bf16x8s p1 = *(const bf16x8s*)&lP[rA1*128 + (cgr^(rA1&7))*8];
    #pragma unroll
    for (int j = 0; j < 4; j++){
      int mcol = wcol + j*16 + l15;
      bf16x8s bg = *(const bf16x8s*)(Gk + (size_t)mcol*128 + kk*32 + lg*8);
      aT[0][j] = MFMA16(p0, bg, aT[0][j], 0,0,0);
      aT[1][j] = MFMA16(p1, bg, aT[1][j], 0,0,0);
    }
  }
  // denom^2 partials
  #pragma unroll
  for (int i = 0; i < 2; i++){
    #pragma unroll
    for (int r = 0; r < 4; r++){
      int rowl = wr + i*16 + lg*4 + r;
      float sd = 0.f;
      #pragma unroll
      for (int j = 0; j < 4; j++) sd += aT[i][j][r] * aS[i][j][r];
      #pragma unroll
      for (int o = 1; o < 16; o <<= 1) sd += __shfl_xor(sd, o);
      if (l15 == 0) lDen[rowl][w&1] = sd;
    }
  }
  __syncthreads();

  if (tid < 128){
    int rowl = tid;
    float Z    = lZ[rowl][0] + lZ[rowl][1];
    float num  = (lNum[rowl][0] + lNum[rowl][1]) / Z;
    float den2 = lDen[rowl][0] + lDen[rowl][1];
    float den  = fmaxf(sqrtf(fmaxf(den2, 0.0f)), 1e-12f);
    x2[(size_t)(q0 + rowl)*256 + kb] = expf(lsp[0]) * num / den;
  }
}

// ---------------------------------------------------------------------------
extern "C" void kernel_launch(void* const* d_in, const int* in_sizes, int n_in,
                              void* d_out, int out_size, void* d_ws, size_t ws_size,
                              hipStream_t stream)
{
  (void)in_sizes; (void)n_in; (void)out_size; (void)ws_size;
  const float* qx  = (const float*)d_in[0];
  const float* kx  = (const float*)d_in[1];
  const void*  mask= d_in[2];
  const float* lsp = (const float*)d_in[3];
  const float* g_q = (const float*)d_in[4];
  const float* b_q = (const float*)d_in[5];
  const float* g_k = (const float*)d_in[6];
  // d_in[7] (b_k): softmax-invariant per-q constant, dropped
  const float* wq  = (const float*)d_in[8];
  const float* wk  = (const float*)d_in[9];
  const float* w1  = (const float*)d_in[10];
  const float* b1  = (const float*)d_in[11];
  const float* w2  = (const float*)d_in[12];
  const float* b2  = (const float*)d_in[13];

  char* ws = (char*)d_ws;
  u16* kxb  = (u16*)(ws + OFF_KXB);
  u16* Gm   = (u16*)(ws + OFF_G);
  u16* w2b  = (u16*)(ws + OFF_W2B);
  u16* hbuf = (u16*)(ws + OFF_H);
  u16* w1b  = (u16*)(ws + OFF_W1B);
  u16* qln  = (u16*)(ws + OFF_QLN);
  u16* qhat = (u16*)(ws + OFF_QHAT);
  u16* qxb  = (u16*)(ws + OFF_QXB);
  u16* pbuf = (u16*)(ws + OFF_P);
  u16* m2   = (u16*)(ws + OFF_M2);
  u16* wqb  = (u16*)(ws + OFF_WQB);
  u16* wkt  = (u16*)(ws + OFF_WKT);
  float* km  = (float*)(ws + OFF_KM);
  float* kr  = (float*)(ws + OFF_KR);
  float* t2s = (float*)(ws + OFF_T2);
  int*   flag= (int*)(ws + OFF_FLAG);
  float* x1o = (float*)d_out;
  float* x2o = (float*)d_out + 512*1000;

  k_phaseA<<<dim3(12241), dim3(256), 0, stream>>>(
      qx, kx, (const int*)mask, g_q, b_q, wq, wk, w1, w2,
      kxb, km, kr, qln, qhat, qxb, wqb, wkt, w1b, w2b, t2s, flag);
  k_phaseB<<<dim3(1344), dim3(256), 0, stream>>>(
      qln, wqb, pbuf, kxb, Gm, qxb, w1b, b1, hbuf);
  k_phaseC<<<dim3(192), dim3(256), 0, stream>>>(
      pbuf, wkt, g_k, m2, t2s, hbuf, w2b, b2, x1o);
  k_attn<<<dim3(256, 4), dim3(512), 0, stream>>>(
      kxb, Gm, m2, qhat, km, kr, t2s, mask, flag, lsp, x2o);
}